// Round 3
// baseline (380.591 us; speedup 1.0000x reference)
//
#include <hip/hip_runtime.h>
#include <hip/hip_bf16.h>

// FocalLoss: output [B=4,C=16,D=64,H=128,W=128] f32, target [B,D,H,W] int.
// result = sum(fw*ce)/sum(fw), fw=(1-logit[t])^2 (RAW logit), ce = lse - logit[t].

constexpr int C_CH  = 16;
constexpr int DHW   = 64 * 128 * 128;      // 1,048,576 = 2^20
constexpr int NPOS  = 4 * DHW;             // 4,194,304 positions
constexpr int BLOCK = 256;
constexpr int POS_PER_THREAD = 4;          // float4
constexpr int NBLOCKS = NPOS / (BLOCK * POS_PER_THREAD);   // 4096

__device__ __forceinline__ float get4(const float4& v, int j) {
    switch (j) { case 0: return v.x; case 1: return v.y; case 2: return v.z; default: return v.w; }
}

__global__ __launch_bounds__(BLOCK) void focal_main(
        const float* __restrict__ out, const int* __restrict__ tgt,
        float* __restrict__ partials /* [2 * NBLOCKS] */) {
    const int tid = blockIdx.x * BLOCK + threadIdx.x;
    const int pos = tid * POS_PER_THREAD;              // < 2^23, int ok
    const int b   = pos >> 20;                          // pos / DHW
    const int s   = pos & (DHW - 1);

    const float* base = out + (size_t)b * C_CH * DHW + s;

    // 16 channel float4 loads (coalesced dwordx4 within each channel plane)
    float4 x[C_CH];
#pragma unroll
    for (int c = 0; c < C_CH; ++c)
        x[c] = *reinterpret_cast<const float4*>(base + (size_t)c * DHW);

    const int4 t4 = *reinterpret_cast<const int4*>(tgt + pos);

    float a1 = 0.0f, a2 = 0.0f;   // sum fw*ce, sum fw
#pragma unroll
    for (int j = 0; j < POS_PER_THREAD; ++j) {
        const int t = (j == 0) ? t4.x : (j == 1) ? t4.y : (j == 2) ? t4.z : t4.w;
        float m = -1e30f;
#pragma unroll
        for (int c = 0; c < C_CH; ++c) m = fmaxf(m, get4(x[c], j));
        float se = 0.0f, p = 0.0f;
#pragma unroll
        for (int c = 0; c < C_CH; ++c) {
            const float xv = get4(x[c], j);
            se += __expf(xv - m);
            if (c == t) p = xv;     // predicated select, compile-time c
        }
        const float lse = m + __logf(se);
        const float ce  = lse - p;
        const float om  = 1.0f - p;
        const float fw  = om * om;
        a1 += fw * ce;
        a2 += fw;
    }

    // 64-lane butterfly reduce
#pragma unroll
    for (int off = 32; off; off >>= 1) {
        a1 += __shfl_xor(a1, off, 64);
        a2 += __shfl_xor(a2, off, 64);
    }

    __shared__ float s1[BLOCK / 64], s2[BLOCK / 64];
    const int wid  = threadIdx.x >> 6;
    const int lane = threadIdx.x & 63;
    if (lane == 0) { s1[wid] = a1; s2[wid] = a2; }
    __syncthreads();
    if (threadIdx.x == 0) {
        float t1 = 0.0f, t2 = 0.0f;
#pragma unroll
        for (int w = 0; w < BLOCK / 64; ++w) { t1 += s1[w]; t2 += s2[w]; }
        partials[blockIdx.x]            = t1;
        partials[NBLOCKS + blockIdx.x]  = t2;
    }
}

__global__ __launch_bounds__(BLOCK) void focal_final(
        const float* __restrict__ partials, float* __restrict__ result) {
    double a1 = 0.0, a2 = 0.0;
    for (int i = threadIdx.x; i < NBLOCKS; i += BLOCK) {
        a1 += (double)partials[i];
        a2 += (double)partials[NBLOCKS + i];
    }
#pragma unroll
    for (int off = 32; off; off >>= 1) {
        a1 += __shfl_xor(a1, off, 64);
        a2 += __shfl_xor(a2, off, 64);
    }
    __shared__ double w1[BLOCK / 64], w2[BLOCK / 64];
    const int wid  = threadIdx.x >> 6;
    const int lane = threadIdx.x & 63;
    if (lane == 0) { w1[wid] = a1; w2[wid] = a2; }
    __syncthreads();
    if (threadIdx.x == 0) {
        double t1 = 0.0, t2 = 0.0;
#pragma unroll
        for (int w = 0; w < BLOCK / 64; ++w) { t1 += w1[w]; t2 += w2[w]; }
        result[0] = (float)(t1 / t2);
    }
}

extern "C" void kernel_launch(void* const* d_in, const int* in_sizes, int n_in,
                              void* d_out, int out_size, void* d_ws, size_t ws_size,
                              hipStream_t stream) {
    const float* output = (const float*)d_in[0];
    const int*   target = (const int*)d_in[1];
    float* partials = (float*)d_ws;          // 2*NBLOCKS floats = 32 KB
    float* result   = (float*)d_out;

    focal_main<<<NBLOCKS, BLOCK, 0, stream>>>(output, target, partials);
    focal_final<<<1, BLOCK, 0, stream>>>(partials, result);
}